// Round 1
// baseline (544.765 us; speedup 1.0000x reference)
//
#include <hip/hip_runtime.h>
#include <math.h>

// GCN 3-layer forward for MI355X.
// Pipeline per call (graph-capture safe, all on `stream`):
//   1. histogram in-degrees -> dinv = rsqrt(deg+1)
//   2. exclusive scan (2-level) -> CSR row offsets; atomic scatter -> csr_src
//   3. per layer: GEMM (hn = dinv * (A@W)) -> CSR aggregation
//      (agg = hn[self] + sum hn[src]; out = act(dinv*agg + b))
//   4. layer 3 aggregation fuses bias + log_softmax (wave-per-node, 40 lanes)

#define F_IN  256
#define F_MID 128
#define F_OUT 40

// ---------------- degree / CSR build ----------------

__global__ __launch_bounds__(256) void k_count(const int* __restrict__ dst,
                                               int* __restrict__ cnt, int E) {
    int e = blockIdx.x * 256 + threadIdx.x;
    if (e < E) atomicAdd(&cnt[dst[e]], 1);
}

__global__ __launch_bounds__(256) void k_dinv(const int* __restrict__ cnt,
                                              float* __restrict__ dinv, int n) {
    int i = blockIdx.x * 256 + threadIdx.x;
    if (i < n) dinv[i] = rsqrtf((float)(cnt[i] + 1));  // +1 self loop
}

__global__ __launch_bounds__(256) void k_scan1(const int* __restrict__ cnt,
                                               int* __restrict__ rofs,
                                               int* __restrict__ bsum, int n) {
    __shared__ int s[256];
    int t = threadIdx.x;
    int i = blockIdx.x * 256 + t;
    int v = (i < n) ? cnt[i] : 0;
    s[t] = v;
    __syncthreads();
#pragma unroll
    for (int off = 1; off < 256; off <<= 1) {
        int x = (t >= off) ? s[t - off] : 0;
        __syncthreads();
        s[t] += x;
        __syncthreads();
    }
    if (i < n) rofs[i + 1] = s[t];          // inclusive partial
    if (t == 255) bsum[blockIdx.x] = s[255];
    if (i == 0) rofs[0] = 0;
}

__global__ __launch_bounds__(256) void k_scan2(int* __restrict__ bsum, int nb) {
    __shared__ int s[256];
    int t = threadIdx.x;
    int v = (t < nb) ? bsum[t] : 0;
    s[t] = v;
    __syncthreads();
#pragma unroll
    for (int off = 1; off < 256; off <<= 1) {
        int x = (t >= off) ? s[t - off] : 0;
        __syncthreads();
        s[t] += x;
        __syncthreads();
    }
    if (t < nb) bsum[t] = s[t] - v;          // exclusive block offsets
}

__global__ __launch_bounds__(256) void k_scan3(int* __restrict__ rofs,
                                               const int* __restrict__ bsum, int n) {
    int i = blockIdx.x * 256 + threadIdx.x;
    if (i < n) rofs[i + 1] += bsum[blockIdx.x];
}

__global__ __launch_bounds__(256) void k_cursor(const int* __restrict__ rofs,
                                                int* __restrict__ cursor, int n) {
    int i = blockIdx.x * 256 + threadIdx.x;
    if (i < n) cursor[i] = rofs[i];
}

__global__ __launch_bounds__(256) void k_scatter(const int* __restrict__ src,
                                                 const int* __restrict__ dst,
                                                 int* __restrict__ cursor,
                                                 int* __restrict__ csr, int E) {
    int e = blockIdx.x * 256 + threadIdx.x;
    if (e < E) {
        int d = dst[e];
        int p = atomicAdd(&cursor[d], 1);
        csr[p] = src[e];
    }
}

// ---------------- GEMM: out[row] = dinv[row] * (A[row,:K] @ W[:K,:128]) ----------------
// block = 256 threads, 64 rows x 128 cols; thread = 4 rows x 8 cols.

template <int K>
__global__ __launch_bounds__(256) void gemm_m128(const float* __restrict__ A,
                                                 const float* __restrict__ Wg,
                                                 const float* __restrict__ dinv,
                                                 float* __restrict__ out, int n) {
    __shared__ float As[64][36];     // +4 pad keeps 16B alignment, spreads banks
    __shared__ float Ws[32][128];
    const int t = threadIdx.x;
    const int row0 = blockIdx.x * 64;
    const int rg = t >> 4;   // 0..15 -> rows rg*4 .. rg*4+3
    const int cg = t & 15;   // 0..15 -> cols cg*8 .. cg*8+7
    float acc[4][8];
#pragma unroll
    for (int r = 0; r < 4; ++r)
#pragma unroll
        for (int c = 0; c < 8; ++c) acc[r][c] = 0.f;

    for (int k0 = 0; k0 < K; k0 += 32) {
#pragma unroll
        for (int s = 0; s < 2; ++s) {          // A chunk: 64x32 floats
            int slot = t + s * 256;            // 0..511 float4 slots
            int r = slot >> 3;
            int kv = slot & 7;
            int row = row0 + r;
            float4 av = make_float4(0.f, 0.f, 0.f, 0.f);
            if (row < n) av = *(const float4*)(A + (size_t)row * K + k0 + kv * 4);
            *(float4*)&As[r][kv * 4] = av;
        }
#pragma unroll
        for (int s = 0; s < 4; ++s) {          // W chunk: 32x128 floats
            int slot = t + s * 256;            // 0..1023 float4 slots
            int kk = slot >> 5;
            int mv = slot & 31;
            *(float4*)&Ws[kk][mv * 4] = *(const float4*)(Wg + (k0 + kk) * 128 + mv * 4);
        }
        __syncthreads();
#pragma unroll
        for (int kk4 = 0; kk4 < 8; ++kk4) {
            float a[4][4];
#pragma unroll
            for (int r = 0; r < 4; ++r) {
                float4 av = *(const float4*)&As[rg * 4 + r][kk4 * 4];
                a[r][0] = av.x; a[r][1] = av.y; a[r][2] = av.z; a[r][3] = av.w;
            }
#pragma unroll
            for (int j = 0; j < 4; ++j) {
                float4 w0 = *(const float4*)&Ws[kk4 * 4 + j][cg * 8];
                float4 w1 = *(const float4*)&Ws[kk4 * 4 + j][cg * 8 + 4];
                float wv[8] = {w0.x, w0.y, w0.z, w0.w, w1.x, w1.y, w1.z, w1.w};
#pragma unroll
                for (int r = 0; r < 4; ++r)
#pragma unroll
                    for (int c = 0; c < 8; ++c) acc[r][c] += a[r][j] * wv[c];
            }
        }
        __syncthreads();
    }
#pragma unroll
    for (int r = 0; r < 4; ++r) {
        int row = row0 + rg * 4 + r;
        if (row < n) {
            float dv = dinv[row];
            float4 o0, o1;
            o0.x = acc[r][0] * dv; o0.y = acc[r][1] * dv;
            o0.z = acc[r][2] * dv; o0.w = acc[r][3] * dv;
            o1.x = acc[r][4] * dv; o1.y = acc[r][5] * dv;
            o1.z = acc[r][6] * dv; o1.w = acc[r][7] * dv;
            *(float4*)(out + (size_t)row * 128 + cg * 8) = o0;
            *(float4*)(out + (size_t)row * 128 + cg * 8 + 4) = o1;
        }
    }
}

// GEMM K=128, M=40 (layer 3). 64 rows/block, thread = 2 rows x 5 cols.
__global__ __launch_bounds__(256) void gemm_m40(const float* __restrict__ A,
                                                const float* __restrict__ Wg,
                                                const float* __restrict__ dinv,
                                                float* __restrict__ out, int n) {
    const int K = 128;
    __shared__ float As[64][36];
    __shared__ float Wt[40][36];   // transposed: Wt[m][kk]
    const int t = threadIdx.x;
    const int row0 = blockIdx.x * 64;
    const int rg = t >> 3;  // 0..31 -> rows rg*2, rg*2+1
    const int cg = t & 7;   // 0..7  -> cols cg*5 .. cg*5+4
    float acc[2][5];
#pragma unroll
    for (int r = 0; r < 2; ++r)
#pragma unroll
        for (int c = 0; c < 5; ++c) acc[r][c] = 0.f;

    for (int k0 = 0; k0 < K; k0 += 32) {
#pragma unroll
        for (int s = 0; s < 2; ++s) {
            int slot = t + s * 256;
            int r = slot >> 3;
            int kv = slot & 7;
            int row = row0 + r;
            float4 av = make_float4(0.f, 0.f, 0.f, 0.f);
            if (row < n) av = *(const float4*)(A + (size_t)row * K + k0 + kv * 4);
            *(float4*)&As[r][kv * 4] = av;
        }
        for (int s = t; s < 32 * 40; s += 256) {
            int kk = s & 31;
            int m = s >> 5;
            Wt[m][kk] = Wg[(k0 + kk) * 40 + m];
        }
        __syncthreads();
#pragma unroll
        for (int kk4 = 0; kk4 < 8; ++kk4) {
            float4 a0 = *(const float4*)&As[rg * 2][kk4 * 4];
            float4 a1 = *(const float4*)&As[rg * 2 + 1][kk4 * 4];
            float a0a[4] = {a0.x, a0.y, a0.z, a0.w};
            float a1a[4] = {a1.x, a1.y, a1.z, a1.w};
#pragma unroll
            for (int c = 0; c < 5; ++c) {
                float4 wv = *(const float4*)&Wt[cg * 5 + c][kk4 * 4];
                float wa[4] = {wv.x, wv.y, wv.z, wv.w};
#pragma unroll
                for (int j = 0; j < 4; ++j) {
                    acc[0][c] += a0a[j] * wa[j];
                    acc[1][c] += a1a[j] * wa[j];
                }
            }
        }
        __syncthreads();
    }
#pragma unroll
    for (int r = 0; r < 2; ++r) {
        int row = row0 + rg * 2 + r;
        if (row < n) {
            float dv = dinv[row];
#pragma unroll
            for (int c = 0; c < 5; ++c)
                out[(size_t)row * 40 + cg * 5 + c] = acc[r][c] * dv;
        }
    }
}

// ---------------- aggregation ----------------
// wave-per-node; F=128 -> float2 per lane. out = relu(dinv*agg + b).
__global__ __launch_bounds__(256) void agg_f128(const float* __restrict__ hn,
                                                const int* __restrict__ rofs,
                                                const int* __restrict__ csr,
                                                const float* __restrict__ dinv,
                                                const float* __restrict__ bias,
                                                float* __restrict__ out, int n) {
    int wid = (blockIdx.x * 256 + threadIdx.x) >> 6;
    int lane = threadIdx.x & 63;
    if (wid >= n) return;
    int v = wid;
    int f = lane * 2;
    float2 acc = *(const float2*)(hn + (size_t)v * 128 + f);  // self loop
    int e0 = rofs[v], e1 = rofs[v + 1];
    int e = e0;
    int s_next = (e < e1) ? csr[e] : 0;
    for (; e < e1;) {
        int s = s_next;
        ++e;
        s_next = (e < e1) ? csr[e] : 0;
        float2 m = *(const float2*)(hn + (size_t)s * 128 + f);
        acc.x += m.x;
        acc.y += m.y;
    }
    float dv = dinv[v];
    float ox = fmaxf(dv * acc.x + bias[f], 0.f);
    float oy = fmaxf(dv * acc.y + bias[f + 1], 0.f);
    *(float2*)(out + (size_t)v * 128 + f) = make_float2(ox, oy);
}

// F=40 aggregation + bias + log_softmax. wave-per-node, lanes 0..39 active.
__global__ __launch_bounds__(256) void agg_f40_lsm(const float* __restrict__ hn,
                                                   const int* __restrict__ rofs,
                                                   const int* __restrict__ csr,
                                                   const float* __restrict__ dinv,
                                                   const float* __restrict__ bias,
                                                   float* __restrict__ out, int n) {
    int wid = (blockIdx.x * 256 + threadIdx.x) >> 6;
    int lane = threadIdx.x & 63;
    if (wid >= n) return;   // uniform per wave
    int v = wid;
    bool act = lane < 40;
    float acc = act ? hn[(size_t)v * 40 + lane] : 0.f;
    int e0 = rofs[v], e1 = rofs[v + 1];
    int e = e0;
    int s_next = (e < e1) ? csr[e] : 0;
    for (; e < e1;) {
        int s = s_next;
        ++e;
        s_next = (e < e1) ? csr[e] : 0;
        if (act) acc += hn[(size_t)s * 40 + lane];
    }
    float val = act ? (dinv[v] * acc + bias[lane]) : -3.402823466e38f;
    float m = val;
#pragma unroll
    for (int off = 32; off; off >>= 1) m = fmaxf(m, __shfl_xor(m, off));
    float p = act ? __expf(val - m) : 0.f;
    float ssum = p;
#pragma unroll
    for (int off = 32; off; off >>= 1) ssum += __shfl_xor(ssum, off);
    if (act) out[(size_t)v * 40 + lane] = val - m - __logf(ssum);
}

// ---------------- launch ----------------

extern "C" void kernel_launch(void* const* d_in, const int* in_sizes, int n_in,
                              void* d_out, int out_size, void* d_ws, size_t ws_size,
                              hipStream_t stream) {
    const float* x     = (const float*)d_in[0];
    const int*   ei    = (const int*)d_in[1];
    const float* W_in  = (const float*)d_in[2];
    const float* b_in  = (const float*)d_in[3];
    const float* W_mid = (const float*)d_in[4];
    const float* b_mid = (const float*)d_in[5];
    const float* W_out = (const float*)d_in[6];
    const float* b_out = (const float*)d_in[7];
    float* out = (float*)d_out;

    const int N = in_sizes[0] / F_IN;   // 50000
    const int E = in_sizes[1] / 2;      // 800000
    const int* srcp = ei;
    const int* dstp = ei + E;

    char* w = (char*)d_ws;
    float* h1   = (float*)w; w += (size_t)N * 128 * 4;
    float* o1   = (float*)w; w += (size_t)N * 128 * 4;
    float* dinv = (float*)w; w += (size_t)N * 4;
    int* cnt    = (int*)w;   w += (size_t)N * 4;
    int* rofs   = (int*)w;   w += (size_t)(N + 1) * 4;
    int* cursor = (int*)w;   w += (size_t)N * 4;
    int* bsum   = (int*)w;   w += 1024;
    int* csr    = (int*)w;   w += (size_t)E * 4;

    const int nbN = (N + 255) / 256;
    const int nbE = (E + 255) / 256;
    const int nbW = (N * 64 + 255) / 256;  // wave-per-node grids
    const int nbG = (N + 63) / 64;

    hipMemsetAsync(cnt, 0, (size_t)N * 4, stream);
    k_count<<<nbE, 256, 0, stream>>>(dstp, cnt, E);
    k_dinv<<<nbN, 256, 0, stream>>>(cnt, dinv, N);
    k_scan1<<<nbN, 256, 0, stream>>>(cnt, rofs, bsum, N);
    k_scan2<<<1, 256, 0, stream>>>(bsum, nbN);
    k_scan3<<<nbN, 256, 0, stream>>>(rofs, bsum, N);
    k_cursor<<<nbN, 256, 0, stream>>>(rofs, cursor, N);
    k_scatter<<<nbE, 256, 0, stream>>>(srcp, dstp, cursor, csr, E);

    // layer 1: x[N,256] -> h1 -> o1 (relu)
    gemm_m128<256><<<nbG, 256, 0, stream>>>(x, W_in, dinv, h1, N);
    agg_f128<<<nbW, 256, 0, stream>>>(h1, rofs, csr, dinv, b_in, o1, N);
    // layer 2: o1 -> h1 -> o1 (relu)
    gemm_m128<128><<<nbG, 256, 0, stream>>>(o1, W_mid, dinv, h1, N);
    agg_f128<<<nbW, 256, 0, stream>>>(h1, rofs, csr, dinv, b_mid, o1, N);
    // layer 3: o1 -> h1[N,40] -> out (log_softmax)
    gemm_m40<<<nbG, 256, 0, stream>>>(o1, W_out, dinv, h1, N);
    agg_f40_lsm<<<nbW, 256, 0, stream>>>(h1, rofs, csr, dinv, b_out, out, N);
}

// Round 2
// 428.101 us; speedup vs baseline: 1.2725x; 1.2725x over previous
//
#include <hip/hip_runtime.h>
#include <math.h>

// GCN 3-layer forward for MI355X.
// R2: hn stored bf16 (halves gather traffic), aggregation processes 4 edges
// per wave-iteration (16 lanes x 16B each) -> 4 independent load chains.
// Layer-3 agg: 2 edges per wave (20 lanes x 4B), fused bias+log_softmax.

#define F_IN  256
#define F_MID 128
#define F_OUT 40

__device__ __forceinline__ unsigned int f2bf(float f) {
    unsigned int u = __float_as_uint(f);
    return (u + 0x7fffu + ((u >> 16) & 1u)) >> 16;   // RNE bf16
}
__device__ __forceinline__ float bf_lo(unsigned int u) { return __uint_as_float(u << 16); }
__device__ __forceinline__ float bf_hi(unsigned int u) { return __uint_as_float(u & 0xffff0000u); }

// ---------------- degree / CSR build ----------------

__global__ __launch_bounds__(256) void k_count(const int* __restrict__ dst,
                                               int* __restrict__ cnt, int E) {
    int e = blockIdx.x * 256 + threadIdx.x;
    if (e < E) atomicAdd(&cnt[dst[e]], 1);
}

__global__ __launch_bounds__(256) void k_dinv(const int* __restrict__ cnt,
                                              float* __restrict__ dinv, int n) {
    int i = blockIdx.x * 256 + threadIdx.x;
    if (i < n) dinv[i] = rsqrtf((float)(cnt[i] + 1));  // +1 self loop
}

__global__ __launch_bounds__(256) void k_scan1(const int* __restrict__ cnt,
                                               int* __restrict__ rofs,
                                               int* __restrict__ bsum, int n) {
    __shared__ int s[256];
    int t = threadIdx.x;
    int i = blockIdx.x * 256 + t;
    int v = (i < n) ? cnt[i] : 0;
    s[t] = v;
    __syncthreads();
#pragma unroll
    for (int off = 1; off < 256; off <<= 1) {
        int x = (t >= off) ? s[t - off] : 0;
        __syncthreads();
        s[t] += x;
        __syncthreads();
    }
    if (i < n) rofs[i + 1] = s[t];
    if (t == 255) bsum[blockIdx.x] = s[255];
    if (i == 0) rofs[0] = 0;
}

__global__ __launch_bounds__(256) void k_scan2(int* __restrict__ bsum, int nb) {
    __shared__ int s[256];
    int t = threadIdx.x;
    int v = (t < nb) ? bsum[t] : 0;
    s[t] = v;
    __syncthreads();
#pragma unroll
    for (int off = 1; off < 256; off <<= 1) {
        int x = (t >= off) ? s[t - off] : 0;
        __syncthreads();
        s[t] += x;
        __syncthreads();
    }
    if (t < nb) bsum[t] = s[t] - v;
}

__global__ __launch_bounds__(256) void k_scan3(int* __restrict__ rofs,
                                               const int* __restrict__ bsum, int n) {
    int i = blockIdx.x * 256 + threadIdx.x;
    if (i < n) rofs[i + 1] += bsum[blockIdx.x];
}

__global__ __launch_bounds__(256) void k_cursor(const int* __restrict__ rofs,
                                                int* __restrict__ cursor, int n) {
    int i = blockIdx.x * 256 + threadIdx.x;
    if (i < n) cursor[i] = rofs[i];
}

__global__ __launch_bounds__(256) void k_scatter(const int* __restrict__ src,
                                                 const int* __restrict__ dst,
                                                 int* __restrict__ cursor,
                                                 int* __restrict__ csr, int E) {
    int e = blockIdx.x * 256 + threadIdx.x;
    if (e < E) {
        int d = dst[e];
        int p = atomicAdd(&cursor[d], 1);
        csr[p] = src[e];
    }
}

// ---------------- GEMM: hn[row] = bf16(dinv[row] * (A[row,:K] @ W[:K,:128])) ----

template <int K>
__global__ __launch_bounds__(256) void gemm_m128(const float* __restrict__ A,
                                                 const float* __restrict__ Wg,
                                                 const float* __restrict__ dinv,
                                                 unsigned short* __restrict__ hn, int n) {
    __shared__ float As[64][36];
    __shared__ float Ws[32][128];
    const int t = threadIdx.x;
    const int row0 = blockIdx.x * 64;
    const int rg = t >> 4;
    const int cg = t & 15;
    float acc[4][8];
#pragma unroll
    for (int r = 0; r < 4; ++r)
#pragma unroll
        for (int c = 0; c < 8; ++c) acc[r][c] = 0.f;

    for (int k0 = 0; k0 < K; k0 += 32) {
#pragma unroll
        for (int s = 0; s < 2; ++s) {
            int slot = t + s * 256;
            int r = slot >> 3;
            int kv = slot & 7;
            int row = row0 + r;
            float4 av = make_float4(0.f, 0.f, 0.f, 0.f);
            if (row < n) av = *(const float4*)(A + (size_t)row * K + k0 + kv * 4);
            *(float4*)&As[r][kv * 4] = av;
        }
#pragma unroll
        for (int s = 0; s < 4; ++s) {
            int slot = t + s * 256;
            int kk = slot >> 5;
            int mv = slot & 31;
            *(float4*)&Ws[kk][mv * 4] = *(const float4*)(Wg + (k0 + kk) * 128 + mv * 4);
        }
        __syncthreads();
#pragma unroll
        for (int kk4 = 0; kk4 < 8; ++kk4) {
            float a[4][4];
#pragma unroll
            for (int r = 0; r < 4; ++r) {
                float4 av = *(const float4*)&As[rg * 4 + r][kk4 * 4];
                a[r][0] = av.x; a[r][1] = av.y; a[r][2] = av.z; a[r][3] = av.w;
            }
#pragma unroll
            for (int j = 0; j < 4; ++j) {
                float4 w0 = *(const float4*)&Ws[kk4 * 4 + j][cg * 8];
                float4 w1 = *(const float4*)&Ws[kk4 * 4 + j][cg * 8 + 4];
                float wv[8] = {w0.x, w0.y, w0.z, w0.w, w1.x, w1.y, w1.z, w1.w};
#pragma unroll
                for (int r = 0; r < 4; ++r)
#pragma unroll
                    for (int c = 0; c < 8; ++c) acc[r][c] += a[r][j] * wv[c];
            }
        }
        __syncthreads();
    }
#pragma unroll
    for (int r = 0; r < 4; ++r) {
        int row = row0 + rg * 4 + r;
        if (row < n) {
            float dv = dinv[row];
            uint4 pk;
            pk.x = f2bf(acc[r][0] * dv) | (f2bf(acc[r][1] * dv) << 16);
            pk.y = f2bf(acc[r][2] * dv) | (f2bf(acc[r][3] * dv) << 16);
            pk.z = f2bf(acc[r][4] * dv) | (f2bf(acc[r][5] * dv) << 16);
            pk.w = f2bf(acc[r][6] * dv) | (f2bf(acc[r][7] * dv) << 16);
            *(uint4*)(hn + (size_t)row * 128 + cg * 8) = pk;
        }
    }
}

// GEMM K=128, M=40 (layer 3), bf16 output.
__global__ __launch_bounds__(256) void gemm_m40(const float* __restrict__ A,
                                                const float* __restrict__ Wg,
                                                const float* __restrict__ dinv,
                                                unsigned short* __restrict__ hn, int n) {
    const int K = 128;
    __shared__ float As[64][36];
    __shared__ float Wt[40][36];
    const int t = threadIdx.x;
    const int row0 = blockIdx.x * 64;
    const int rg = t >> 3;
    const int cg = t & 7;
    float acc[2][5];
#pragma unroll
    for (int r = 0; r < 2; ++r)
#pragma unroll
        for (int c = 0; c < 5; ++c) acc[r][c] = 0.f;

    for (int k0 = 0; k0 < K; k0 += 32) {
#pragma unroll
        for (int s = 0; s < 2; ++s) {
            int slot = t + s * 256;
            int r = slot >> 3;
            int kv = slot & 7;
            int row = row0 + r;
            float4 av = make_float4(0.f, 0.f, 0.f, 0.f);
            if (row < n) av = *(const float4*)(A + (size_t)row * K + k0 + kv * 4);
            *(float4*)&As[r][kv * 4] = av;
        }
        for (int s = t; s < 32 * 40; s += 256) {
            int kk = s & 31;
            int m = s >> 5;
            Wt[m][kk] = Wg[(k0 + kk) * 40 + m];
        }
        __syncthreads();
#pragma unroll
        for (int kk4 = 0; kk4 < 8; ++kk4) {
            float4 a0 = *(const float4*)&As[rg * 2][kk4 * 4];
            float4 a1 = *(const float4*)&As[rg * 2 + 1][kk4 * 4];
            float a0a[4] = {a0.x, a0.y, a0.z, a0.w};
            float a1a[4] = {a1.x, a1.y, a1.z, a1.w};
#pragma unroll
            for (int c = 0; c < 5; ++c) {
                float4 wv = *(const float4*)&Wt[cg * 5 + c][kk4 * 4];
                float wa[4] = {wv.x, wv.y, wv.z, wv.w};
#pragma unroll
                for (int j = 0; j < 4; ++j) {
                    acc[0][c] += a0a[j] * wa[j];
                    acc[1][c] += a1a[j] * wa[j];
                }
            }
        }
        __syncthreads();
    }
#pragma unroll
    for (int r = 0; r < 2; ++r) {
        int row = row0 + rg * 2 + r;
        if (row < n) {
            float dv = dinv[row];
#pragma unroll
            for (int c = 0; c < 5; ++c)
                hn[(size_t)row * 40 + cg * 5 + c] = (unsigned short)f2bf(acc[r][c] * dv);
        }
    }
}

// ---------------- aggregation ----------------
// F=128 bf16: wave per node, 4 edges/iter (quarter q = lane>>4 handles edge
// i+q; 16 lanes x 16B cover one 256B row). Cross-quarter shfl reduce at end.
__global__ __launch_bounds__(256) void agg128_bf16(const unsigned short* __restrict__ hn,
                                                   const int* __restrict__ rofs,
                                                   const int* __restrict__ csr,
                                                   const float* __restrict__ dinv,
                                                   const float* __restrict__ bias,
                                                   float* __restrict__ out, int n) {
    int wid = (blockIdx.x * 256 + threadIdx.x) >> 6;
    if (wid >= n) return;
    const int v = wid;
    const int lane = threadIdx.x & 63;
    const int q = lane >> 4;
    const int sub = lane & 15;
    float acc[8];
#pragma unroll
    for (int k = 0; k < 8; ++k) acc[k] = 0.f;
    const int e0 = rofs[v];
    const int total = rofs[v + 1] - e0 + 1;   // + self loop (i==0)
    for (int i = q; i < total; i += 4) {
        int s = (i == 0) ? v : csr[e0 + i - 1];
        uint4 u = *(const uint4*)(hn + (size_t)s * 128 + sub * 8);
        acc[0] += bf_lo(u.x); acc[1] += bf_hi(u.x);
        acc[2] += bf_lo(u.y); acc[3] += bf_hi(u.y);
        acc[4] += bf_lo(u.z); acc[5] += bf_hi(u.z);
        acc[6] += bf_lo(u.w); acc[7] += bf_hi(u.w);
    }
#pragma unroll
    for (int k = 0; k < 8; ++k) {
        acc[k] += __shfl_xor(acc[k], 16);
        acc[k] += __shfl_xor(acc[k], 32);
    }
    if (q == 0) {
        float dv = dinv[v];
        float4 b0 = *(const float4*)(bias + sub * 8);
        float4 b1 = *(const float4*)(bias + sub * 8 + 4);
        float4 o0, o1;
        o0.x = fmaxf(dv * acc[0] + b0.x, 0.f);
        o0.y = fmaxf(dv * acc[1] + b0.y, 0.f);
        o0.z = fmaxf(dv * acc[2] + b0.z, 0.f);
        o0.w = fmaxf(dv * acc[3] + b0.w, 0.f);
        o1.x = fmaxf(dv * acc[4] + b1.x, 0.f);
        o1.y = fmaxf(dv * acc[5] + b1.y, 0.f);
        o1.z = fmaxf(dv * acc[6] + b1.z, 0.f);
        o1.w = fmaxf(dv * acc[7] + b1.w, 0.f);
        *(float4*)(out + (size_t)v * 128 + sub * 8) = o0;
        *(float4*)(out + (size_t)v * 128 + sub * 8 + 4) = o1;
    }
}

// F=40 bf16 agg + bias + log_softmax. Wave per node, 2 edges/iter
// (half h = lane>>5; lanes sl<20 each cover 2 feats via one u32).
__global__ __launch_bounds__(256) void agg40_lsm_bf16(const unsigned short* __restrict__ hn,
                                                      const int* __restrict__ rofs,
                                                      const int* __restrict__ csr,
                                                      const float* __restrict__ dinv,
                                                      const float* __restrict__ bias,
                                                      float* __restrict__ out, int n) {
    int wid = (blockIdx.x * 256 + threadIdx.x) >> 6;
    if (wid >= n) return;
    const int v = wid;
    const int lane = threadIdx.x & 63;
    const int h = lane >> 5;
    const int sl = lane & 31;
    const bool act = sl < 20;
    float a0 = 0.f, a1 = 0.f;
    const int e0 = rofs[v];
    const int total = rofs[v + 1] - e0 + 1;
    for (int i = h; i < total; i += 2) {
        int s = (i == 0) ? v : csr[e0 + i - 1];
        if (act) {
            unsigned int u = *(const unsigned int*)(hn + (size_t)s * 40 + sl * 2);
            a0 += bf_lo(u);
            a1 += bf_hi(u);
        }
    }
    a0 += __shfl_xor(a0, 32);
    a1 += __shfl_xor(a1, 32);
    float dv = dinv[v];
    float v0 = act ? (dv * a0 + bias[sl * 2])     : -3.402823466e38f;
    float v1 = act ? (dv * a1 + bias[sl * 2 + 1]) : -3.402823466e38f;
    float m = fmaxf(v0, v1);
#pragma unroll
    for (int off = 16; off; off >>= 1) m = fmaxf(m, __shfl_xor(m, off));
    float p = act ? (__expf(v0 - m) + __expf(v1 - m)) : 0.f;
#pragma unroll
    for (int off = 16; off; off >>= 1) p += __shfl_xor(p, off);
    if (h == 0 && act) {
        float ls = __logf(p);
        *(float2*)(out + (size_t)v * 40 + sl * 2) = make_float2(v0 - m - ls, v1 - m - ls);
    }
}

// ---------------- launch ----------------

extern "C" void kernel_launch(void* const* d_in, const int* in_sizes, int n_in,
                              void* d_out, int out_size, void* d_ws, size_t ws_size,
                              hipStream_t stream) {
    const float* x     = (const float*)d_in[0];
    const int*   ei    = (const int*)d_in[1];
    const float* W_in  = (const float*)d_in[2];
    const float* b_in  = (const float*)d_in[3];
    const float* W_mid = (const float*)d_in[4];
    const float* b_mid = (const float*)d_in[5];
    const float* W_out = (const float*)d_in[6];
    const float* b_out = (const float*)d_in[7];
    float* out = (float*)d_out;

    const int N = in_sizes[0] / F_IN;   // 50000
    const int E = in_sizes[1] / 2;      // 800000
    const int* srcp = ei;
    const int* dstp = ei + E;

    char* w = (char*)d_ws;
    unsigned short* hn = (unsigned short*)w; w += (size_t)N * 128 * 2;  // bf16 hn (layers 1/2; 40-col reuses)
    float* o1   = (float*)w; w += (size_t)N * 128 * 4;
    float* dinv = (float*)w; w += (size_t)N * 4;
    int* cnt    = (int*)w;   w += (size_t)N * 4;
    int* rofs   = (int*)w;   w += (size_t)(N + 1) * 4;
    int* cursor = (int*)w;   w += (size_t)N * 4;
    int* bsum   = (int*)w;   w += 1024;
    int* csr    = (int*)w;   w += (size_t)E * 4;

    const int nbN = (N + 255) / 256;
    const int nbE = (E + 255) / 256;
    const int nbW = (N * 64 + 255) / 256;
    const int nbG = (N + 63) / 64;

    hipMemsetAsync(cnt, 0, (size_t)N * 4, stream);
    k_count<<<nbE, 256, 0, stream>>>(dstp, cnt, E);
    k_dinv<<<nbN, 256, 0, stream>>>(cnt, dinv, N);
    k_scan1<<<nbN, 256, 0, stream>>>(cnt, rofs, bsum, N);
    k_scan2<<<1, 256, 0, stream>>>(bsum, nbN);
    k_scan3<<<nbN, 256, 0, stream>>>(rofs, bsum, N);
    k_cursor<<<nbN, 256, 0, stream>>>(rofs, cursor, N);
    k_scatter<<<nbE, 256, 0, stream>>>(srcp, dstp, cursor, csr, E);

    // layer 1: x[N,256] -> hn(bf16) -> o1 (relu, f32)
    gemm_m128<256><<<nbG, 256, 0, stream>>>(x, W_in, dinv, hn, N);
    agg128_bf16<<<nbW, 256, 0, stream>>>(hn, rofs, csr, dinv, b_in, o1, N);
    // layer 2
    gemm_m128<128><<<nbG, 256, 0, stream>>>(o1, W_mid, dinv, hn, N);
    agg128_bf16<<<nbW, 256, 0, stream>>>(hn, rofs, csr, dinv, b_mid, o1, N);
    // layer 3: o1 -> hn40(bf16) -> out (log_softmax)
    gemm_m40<<<nbG, 256, 0, stream>>>(o1, W_out, dinv, hn, N);
    agg40_lsm_bf16<<<nbW, 256, 0, stream>>>(hn, rofs, csr, dinv, b_out, out, N);
}

// Round 3
// 339.045 us; speedup vs baseline: 1.6068x; 1.2627x over previous
//
#include <hip/hip_runtime.h>
#include <hip/hip_bf16.h>
#include <math.h>

// GCN 3-layer forward, MI355X. R3: MFMA bf16 GEMMs (W pre-packed to frag
// order, whole-W in LDS, barrier-free K-loop), bf16 activations everywhere,
// agg 8-rows-in-flight, fused CSR-build epilogue.

#define F_IN  256
#define F_MID 128
#define F_OUT 40

typedef __attribute__((ext_vector_type(8))) short bf16x8;
typedef __attribute__((ext_vector_type(4))) float f32x4;

union FragU {
    bf16x8 v;
    __hip_bfloat162 h2[4];
    uint4 u;
    unsigned short s[8];
};

__device__ __forceinline__ unsigned int f2bf(float f) {
    unsigned int u = __float_as_uint(f);
    return (u + 0x7fffu + ((u >> 16) & 1u)) >> 16;   // RNE bf16
}
__device__ __forceinline__ float bf_lo(unsigned int u) { return __uint_as_float(u << 16); }
__device__ __forceinline__ float bf_hi(unsigned int u) { return __uint_as_float(u & 0xffff0000u); }

// ---------------- degree / CSR build ----------------

__global__ __launch_bounds__(256) void k_count(const int* __restrict__ dst,
                                               int* __restrict__ cnt, int E) {
    int e = blockIdx.x * 256 + threadIdx.x;
    if (e < E) atomicAdd(&cnt[dst[e]], 1);
}

__global__ __launch_bounds__(256) void k_scan1(const int* __restrict__ cnt,
                                               int* __restrict__ rofs,
                                               int* __restrict__ bsum, int n) {
    __shared__ int s[256];
    int t = threadIdx.x;
    int i = blockIdx.x * 256 + t;
    int v = (i < n) ? cnt[i] : 0;
    s[t] = v;
    __syncthreads();
#pragma unroll
    for (int off = 1; off < 256; off <<= 1) {
        int x = (t >= off) ? s[t - off] : 0;
        __syncthreads();
        s[t] += x;
        __syncthreads();
    }
    if (i < n) rofs[i + 1] = s[t];
    if (t == 255) bsum[blockIdx.x] = s[255];
    if (i == 0) rofs[0] = 0;
}

__global__ __launch_bounds__(256) void k_scan2(int* __restrict__ bsum, int nb) {
    __shared__ int s[256];
    int t = threadIdx.x;
    int v = (t < nb) ? bsum[t] : 0;
    s[t] = v;
    __syncthreads();
#pragma unroll
    for (int off = 1; off < 256; off <<= 1) {
        int x = (t >= off) ? s[t - off] : 0;
        __syncthreads();
        s[t] += x;
        __syncthreads();
    }
    if (t < nb) bsum[t] = s[t] - v;
}

// finalize rofs, derive cursor and dinv in one pass
__global__ __launch_bounds__(256) void k_scan3(int* __restrict__ rofs,
                                               const int* __restrict__ bsum,
                                               const int* __restrict__ cnt,
                                               int* __restrict__ cursor,
                                               float* __restrict__ dinv, int n) {
    int i = blockIdx.x * 256 + threadIdx.x;
    if (i < n) {
        int incl = rofs[i + 1] + bsum[blockIdx.x];
        rofs[i + 1] = incl;
        int c = cnt[i];
        cursor[i] = incl - c;
        dinv[i] = rsqrtf((float)(c + 1));
    }
}

__global__ __launch_bounds__(256) void k_scatter(const int* __restrict__ src,
                                                 const int* __restrict__ dst,
                                                 int* __restrict__ cursor,
                                                 int* __restrict__ csr, int E) {
    int e = blockIdx.x * 256 + threadIdx.x;
    if (e < E) {
        int d = dst[e];
        int p = atomicAdd(&cursor[d], 1);
        csr[p] = src[e];
    }
}

// ---------------- W pre-pack: W[K][M] f32 -> Wp[(k/8)*Mp + n][8] bf16 ----------------
// one flat launch covering all three weight matrices
__global__ __launch_bounds__(256) void k_prepW(const float* __restrict__ W1,
                                               const float* __restrict__ W2,
                                               const float* __restrict__ W3,
                                               unsigned short* __restrict__ Wp1,
                                               unsigned short* __restrict__ Wp2,
                                               unsigned short* __restrict__ Wp3) {
    int t = blockIdx.x * 256 + threadIdx.x;
    const float* W; unsigned short* Wp; int M, Mp, kc, nn;
    if (t < 4096)        { W = W1; Wp = Wp1; M = 128; Mp = 128; kc = t >> 7; nn = t & 127; }
    else if (t < 6144)   { t -= 4096; W = W2; Wp = Wp2; M = 128; Mp = 128; kc = t >> 7; nn = t & 127; }
    else if (t < 6912)   { t -= 6144; W = W3; Wp = Wp3; M = 40;  Mp = 48;  kc = t / 48; nn = t % 48; }
    else return;
    FragU o;
#pragma unroll
    for (int j = 0; j < 8; ++j) {
        int k = kc * 8 + j;
        o.s[j] = (nn < M) ? (unsigned short)f2bf(W[k * M + nn]) : 0;
    }
    *(uint4*)&Wp[((size_t)kc * Mp + nn) * 8] = o.u;
}

// ---------------- MFMA GEMM, M=128 out, f32 A (layer 1) ----------------
// block 256 = 4 waves; wave w -> rows blockIdx*64 + w*16, all 128 cols.
// A-frag: row = lane&15, k = (lane>>4)*8 + j. C/D: col=lane&15, row=(lane>>4)*4+reg.
template <int K>
__global__ __launch_bounds__(256) void gemm_mfma_f32A(const float* __restrict__ A,
                                                      const unsigned short* __restrict__ Wp,
                                                      const float* __restrict__ dinv,
                                                      unsigned short* __restrict__ hn, int n) {
    __shared__ unsigned short Wl[K * 128];   // frag order: [(k/8)*128 + col][8]
    const int t = threadIdx.x;
    const int w = t >> 6, lane = t & 63, sub = lane & 15, q = lane >> 4;
    const int row0 = blockIdx.x * 64 + w * 16;
    const int row = row0 + sub;
    const bool rv = row < n;
    const float* ap = A + (size_t)row * K;

    for (int sidx = t; sidx < (K * 128) / 8; sidx += 256)
        *(uint4*)&Wl[sidx * 8] = *(const uint4*)&Wp[(size_t)sidx * 8];
    __syncthreads();

    f32x4 acc[8];
#pragma unroll
    for (int cg = 0; cg < 8; ++cg) acc[cg] = (f32x4)0.f;

    for (int k0 = 0; k0 < K; k0 += 32) {
        FragU af; af.u = make_uint4(0, 0, 0, 0);
        if (rv) {
            float4 f0 = *(const float4*)(ap + k0 + q * 8);
            float4 f1 = *(const float4*)(ap + k0 + q * 8 + 4);
            af.h2[0] = __float22bfloat162_rn(make_float2(f0.x, f0.y));
            af.h2[1] = __float22bfloat162_rn(make_float2(f0.z, f0.w));
            af.h2[2] = __float22bfloat162_rn(make_float2(f1.x, f1.y));
            af.h2[3] = __float22bfloat162_rn(make_float2(f1.z, f1.w));
        }
        const int kc = (k0 >> 3) + q;
#pragma unroll
        for (int cg = 0; cg < 8; ++cg) {
            bf16x8 b = *(const bf16x8*)&Wl[(kc * 128 + cg * 16 + sub) * 8];
            acc[cg] = __builtin_amdgcn_mfma_f32_16x16x32_bf16(af.v, b, acc[cg], 0, 0, 0);
        }
    }

    const int rbase = row0 + q * 4;
    float dv[4];
#pragma unroll
    for (int r = 0; r < 4; ++r) dv[r] = (rbase + r < n) ? dinv[rbase + r] : 0.f;
#pragma unroll
    for (int cg = 0; cg < 8; ++cg)
#pragma unroll
        for (int r = 0; r < 4; ++r) {
            int rr = rbase + r;
            if (rr < n)
                hn[(size_t)rr * 128 + cg * 16 + sub] = (unsigned short)f2bf(acc[cg][r] * dv[r]);
        }
}

// same but A already bf16 (layers 2); K template for reuse
template <int K>
__global__ __launch_bounds__(256) void gemm_mfma_bf16A(const unsigned short* __restrict__ A,
                                                       const unsigned short* __restrict__ Wp,
                                                       const float* __restrict__ dinv,
                                                       unsigned short* __restrict__ hn, int n) {
    __shared__ unsigned short Wl[K * 128];
    const int t = threadIdx.x;
    const int w = t >> 6, lane = t & 63, sub = lane & 15, q = lane >> 4;
    const int row0 = blockIdx.x * 64 + w * 16;
    const int row = row0 + sub;
    const bool rv = row < n;
    const unsigned short* ap = A + (size_t)row * K;

    for (int sidx = t; sidx < (K * 128) / 8; sidx += 256)
        *(uint4*)&Wl[sidx * 8] = *(const uint4*)&Wp[(size_t)sidx * 8];
    __syncthreads();

    f32x4 acc[8];
#pragma unroll
    for (int cg = 0; cg < 8; ++cg) acc[cg] = (f32x4)0.f;

    for (int k0 = 0; k0 < K; k0 += 32) {
        FragU af; af.u = make_uint4(0, 0, 0, 0);
        if (rv) af.u = *(const uint4*)(ap + k0 + q * 8);
        const int kc = (k0 >> 3) + q;
#pragma unroll
        for (int cg = 0; cg < 8; ++cg) {
            bf16x8 b = *(const bf16x8*)&Wl[(kc * 128 + cg * 16 + sub) * 8];
            acc[cg] = __builtin_amdgcn_mfma_f32_16x16x32_bf16(af.v, b, acc[cg], 0, 0, 0);
        }
    }

    const int rbase = row0 + q * 4;
    float dv[4];
#pragma unroll
    for (int r = 0; r < 4; ++r) dv[r] = (rbase + r < n) ? dinv[rbase + r] : 0.f;
#pragma unroll
    for (int cg = 0; cg < 8; ++cg)
#pragma unroll
        for (int r = 0; r < 4; ++r) {
            int rr = rbase + r;
            if (rr < n)
                hn[(size_t)rr * 128 + cg * 16 + sub] = (unsigned short)f2bf(acc[cg][r] * dv[r]);
        }
}

// layer 3: K=128, M=40 (padded 48), bf16 A
__global__ __launch_bounds__(256) void gemm_mfma_m40(const unsigned short* __restrict__ A,
                                                     const unsigned short* __restrict__ Wp,
                                                     const float* __restrict__ dinv,
                                                     unsigned short* __restrict__ hn, int n) {
    const int K = 128;
    __shared__ unsigned short Wl[K * 48];
    const int t = threadIdx.x;
    const int w = t >> 6, lane = t & 63, sub = lane & 15, q = lane >> 4;
    const int row0 = blockIdx.x * 64 + w * 16;
    const int row = row0 + sub;
    const bool rv = row < n;
    const unsigned short* ap = A + (size_t)row * K;

    for (int sidx = t; sidx < (K * 48) / 8; sidx += 256)
        *(uint4*)&Wl[sidx * 8] = *(const uint4*)&Wp[(size_t)sidx * 8];
    __syncthreads();

    f32x4 acc[3];
#pragma unroll
    for (int cg = 0; cg < 3; ++cg) acc[cg] = (f32x4)0.f;

    for (int k0 = 0; k0 < K; k0 += 32) {
        FragU af; af.u = make_uint4(0, 0, 0, 0);
        if (rv) af.u = *(const uint4*)(ap + k0 + q * 8);
        const int kc = (k0 >> 3) + q;
#pragma unroll
        for (int cg = 0; cg < 3; ++cg) {
            bf16x8 b = *(const bf16x8*)&Wl[(kc * 48 + cg * 16 + sub) * 8];
            acc[cg] = __builtin_amdgcn_mfma_f32_16x16x32_bf16(af.v, b, acc[cg], 0, 0, 0);
        }
    }

    const int rbase = row0 + q * 4;
    float dv[4];
#pragma unroll
    for (int r = 0; r < 4; ++r) dv[r] = (rbase + r < n) ? dinv[rbase + r] : 0.f;
#pragma unroll
    for (int cg = 0; cg < 3; ++cg) {
        int col = cg * 16 + sub;
        if (col < 40) {
#pragma unroll
            for (int r = 0; r < 4; ++r) {
                int rr = rbase + r;
                if (rr < n)
                    hn[(size_t)rr * 40 + col] = (unsigned short)f2bf(acc[cg][r] * dv[r]);
            }
        }
    }
}

// ---------------- aggregation ----------------
// F=128 bf16: wave/node, quarter q handles edges i=q,q+4,..., 2-deep unrolled
// (8 row-loads in flight per wave). Output packed bf16 (next layer's A).
__global__ __launch_bounds__(256) void agg128_bf16(const unsigned short* __restrict__ hn,
                                                   const int* __restrict__ rofs,
                                                   const int* __restrict__ csr,
                                                   const float* __restrict__ dinv,
                                                   const float* __restrict__ bias,
                                                   unsigned short* __restrict__ obf, int n) {
    int wid = (blockIdx.x * 256 + threadIdx.x) >> 6;
    if (wid >= n) return;
    const int v = wid;
    const int lane = threadIdx.x & 63;
    const int q = lane >> 4;
    const int sub = lane & 15;
    float acc[8];
#pragma unroll
    for (int k = 0; k < 8; ++k) acc[k] = 0.f;
    const int e0 = rofs[v];
    const int total = rofs[v + 1] - e0 + 1;   // + self loop at i==0
    int i = q;
    for (; i + 4 < total; i += 8) {
        int s0 = (i == 0) ? v : csr[e0 + i - 1];
        int s1 = csr[e0 + i + 3];
        uint4 u0 = *(const uint4*)(hn + (size_t)s0 * 128 + sub * 8);
        uint4 u1 = *(const uint4*)(hn + (size_t)s1 * 128 + sub * 8);
        acc[0] += bf_lo(u0.x); acc[1] += bf_hi(u0.x);
        acc[2] += bf_lo(u0.y); acc[3] += bf_hi(u0.y);
        acc[4] += bf_lo(u0.z); acc[5] += bf_hi(u0.z);
        acc[6] += bf_lo(u0.w); acc[7] += bf_hi(u0.w);
        acc[0] += bf_lo(u1.x); acc[1] += bf_hi(u1.x);
        acc[2] += bf_lo(u1.y); acc[3] += bf_hi(u1.y);
        acc[4] += bf_lo(u1.z); acc[5] += bf_hi(u1.z);
        acc[6] += bf_lo(u1.w); acc[7] += bf_hi(u1.w);
    }
    if (i < total) {
        int s = (i == 0) ? v : csr[e0 + i - 1];
        uint4 u = *(const uint4*)(hn + (size_t)s * 128 + sub * 8);
        acc[0] += bf_lo(u.x); acc[1] += bf_hi(u.x);
        acc[2] += bf_lo(u.y); acc[3] += bf_hi(u.y);
        acc[4] += bf_lo(u.z); acc[5] += bf_hi(u.z);
        acc[6] += bf_lo(u.w); acc[7] += bf_hi(u.w);
    }
#pragma unroll
    for (int k = 0; k < 8; ++k) {
        acc[k] += __shfl_xor(acc[k], 16);
        acc[k] += __shfl_xor(acc[k], 32);
    }
    if (q == 0) {
        float dv = dinv[v];
        float4 b0 = *(const float4*)(bias + sub * 8);
        float4 b1 = *(const float4*)(bias + sub * 8 + 4);
        float o[8];
        o[0] = fmaxf(dv * acc[0] + b0.x, 0.f);
        o[1] = fmaxf(dv * acc[1] + b0.y, 0.f);
        o[2] = fmaxf(dv * acc[2] + b0.z, 0.f);
        o[3] = fmaxf(dv * acc[3] + b0.w, 0.f);
        o[4] = fmaxf(dv * acc[4] + b1.x, 0.f);
        o[5] = fmaxf(dv * acc[5] + b1.y, 0.f);
        o[6] = fmaxf(dv * acc[6] + b1.z, 0.f);
        o[7] = fmaxf(dv * acc[7] + b1.w, 0.f);
        uint4 pk;
        pk.x = f2bf(o[0]) | (f2bf(o[1]) << 16);
        pk.y = f2bf(o[2]) | (f2bf(o[3]) << 16);
        pk.z = f2bf(o[4]) | (f2bf(o[5]) << 16);
        pk.w = f2bf(o[6]) | (f2bf(o[7]) << 16);
        *(uint4*)(obf + (size_t)v * 128 + sub * 8) = pk;
    }
}

// F=40 bf16 agg + bias + log_softmax; half h handles edges i=h,h+2,..., 2-deep.
__global__ __launch_bounds__(256) void agg40_lsm_bf16(const unsigned short* __restrict__ hn,
                                                      const int* __restrict__ rofs,
                                                      const int* __restrict__ csr,
                                                      const float* __restrict__ dinv,
                                                      const float* __restrict__ bias,
                                                      float* __restrict__ out, int n) {
    int wid = (blockIdx.x * 256 + threadIdx.x) >> 6;
    if (wid >= n) return;
    const int v = wid;
    const int lane = threadIdx.x & 63;
    const int h = lane >> 5;
    const int sl = lane & 31;
    const bool act = sl < 20;
    float a0 = 0.f, a1 = 0.f;
    const int e0 = rofs[v];
    const int total = rofs[v + 1] - e0 + 1;
    int i = h;
    for (; i + 2 < total; i += 4) {
        int s0 = (i == 0) ? v : csr[e0 + i - 1];
        int s1 = csr[e0 + i + 1];
        if (act) {
            unsigned int u0 = *(const unsigned int*)(hn + (size_t)s0 * 40 + sl * 2);
            unsigned int u1 = *(const unsigned int*)(hn + (size_t)s1 * 40 + sl * 2);
            a0 += bf_lo(u0) + bf_lo(u1);
            a1 += bf_hi(u0) + bf_hi(u1);
        }
    }
    if (i < total) {
        int s = (i == 0) ? v : csr[e0 + i - 1];
        if (act) {
            unsigned int u = *(const unsigned int*)(hn + (size_t)s * 40 + sl * 2);
            a0 += bf_lo(u);
            a1 += bf_hi(u);
        }
    }
    a0 += __shfl_xor(a0, 32);
    a1 += __shfl_xor(a1, 32);
    float dv = dinv[v];
    float v0 = act ? (dv * a0 + bias[sl * 2])     : -3.402823466e38f;
    float v1 = act ? (dv * a1 + bias[sl * 2 + 1]) : -3.402823466e38f;
    float m = fmaxf(v0, v1);
#pragma unroll
    for (int off = 16; off; off >>= 1) m = fmaxf(m, __shfl_xor(m, off));
    float p = act ? (__expf(v0 - m) + __expf(v1 - m)) : 0.f;
#pragma unroll
    for (int off = 16; off; off >>= 1) p += __shfl_xor(p, off);
    if (h == 0 && act) {
        float ls = __logf(p);
        *(float2*)(out + (size_t)v * 40 + sl * 2) = make_float2(v0 - m - ls, v1 - m - ls);
    }
}

// ---------------- launch ----------------

extern "C" void kernel_launch(void* const* d_in, const int* in_sizes, int n_in,
                              void* d_out, int out_size, void* d_ws, size_t ws_size,
                              hipStream_t stream) {
    const float* x     = (const float*)d_in[0];
    const int*   ei    = (const int*)d_in[1];
    const float* W_in  = (const float*)d_in[2];
    const float* b_in  = (const float*)d_in[3];
    const float* W_mid = (const float*)d_in[4];
    const float* b_mid = (const float*)d_in[5];
    const float* W_out = (const float*)d_in[6];
    const float* b_out = (const float*)d_in[7];
    float* out = (float*)d_out;

    const int N = in_sizes[0] / F_IN;   // 50000
    const int E = in_sizes[1] / 2;      // 800000
    const int* srcp = ei;
    const int* dstp = ei + E;

    char* w = (char*)d_ws;
    unsigned short* hn  = (unsigned short*)w; w += (size_t)N * 128 * 2; // GEMM out (bf16)
    unsigned short* obf = (unsigned short*)w; w += (size_t)N * 128 * 2; // agg out (bf16)
    float* dinv = (float*)w; w += (size_t)N * 4;
    int* cnt    = (int*)w;   w += (size_t)N * 4;
    int* rofs   = (int*)w;   w += (size_t)(N + 1) * 4 + 12;  // keep 16B alignment
    int* cursor = (int*)w;   w += (size_t)N * 4;
    int* bsum   = (int*)w;   w += 1024;
    int* csr    = (int*)w;   w += (size_t)E * 4;
    unsigned short* Wp1 = (unsigned short*)w; w += 32 * 128 * 8 * 2;
    unsigned short* Wp2 = (unsigned short*)w; w += 16 * 128 * 8 * 2;
    unsigned short* Wp3 = (unsigned short*)w; w += 16 * 48 * 8 * 2;

    const int nbN = (N + 255) / 256;
    const int nbE = (E + 255) / 256;
    const int nbW = (N * 64 + 255) / 256;   // wave-per-node grids
    const int nbG = (N + 63) / 64;          // 64 rows per block

    hipMemsetAsync(cnt, 0, (size_t)N * 4, stream);
    k_prepW<<<27, 256, 0, stream>>>(W_in, W_mid, W_out, Wp1, Wp2, Wp3);
    k_count<<<nbE, 256, 0, stream>>>(dstp, cnt, E);
    k_scan1<<<nbN, 256, 0, stream>>>(cnt, rofs, bsum, N);
    k_scan2<<<1, 256, 0, stream>>>(bsum, nbN);
    k_scan3<<<nbN, 256, 0, stream>>>(rofs, bsum, cnt, cursor, dinv, N);
    k_scatter<<<nbE, 256, 0, stream>>>(srcp, dstp, cursor, csr, E);

    // layer 1: x f32 -> hn bf16 -> obf bf16 (relu)
    gemm_mfma_f32A<256><<<nbG, 256, 0, stream>>>(x, Wp1, dinv, hn, N);
    agg128_bf16<<<nbW, 256, 0, stream>>>(hn, rofs, csr, dinv, b_in, obf, N);
    // layer 2
    gemm_mfma_bf16A<128><<<nbG, 256, 0, stream>>>(obf, Wp2, dinv, hn, N);
    agg128_bf16<<<nbW, 256, 0, stream>>>(hn, rofs, csr, dinv, b_mid, obf, N);
    // layer 3: obf -> hn[N,40] bf16 -> out f32 (log_softmax)
    gemm_mfma_m40<<<nbG, 256, 0, stream>>>(obf, Wp3, dinv, hn, N);
    agg40_lsm_bf16<<<nbW, 256, 0, stream>>>(hn, rofs, csr, dinv, b_out, out, N);
}

// Round 4
// 338.861 us; speedup vs baseline: 1.6076x; 1.0005x over previous
//
#include <hip/hip_runtime.h>
#include <hip/hip_bf16.h>
#include <math.h>

// GCN 3-layer forward, MI355X. R4: XCD-partitioned CSR build (count/scatter
// blocks own a dst-range keyed to blockIdx&7 so csr/cnt/cursor lines are
// single-XCD -> no cross-XCD line ping-pong), csr as uint16.
// MFMA bf16 GEMMs, bf16 activations, wave-per-node aggregation.

#define F_IN  256
#define F_MID 128
#define F_OUT 40

typedef __attribute__((ext_vector_type(8))) short bf16x8;
typedef __attribute__((ext_vector_type(4))) float f32x4;

union FragU {
    bf16x8 v;
    __hip_bfloat162 h2[4];
    uint4 u;
    unsigned short s[8];
};

__device__ __forceinline__ unsigned int f2bf(float f) {
    unsigned int u = __float_as_uint(f);
    return (u + 0x7fffu + ((u >> 16) & 1u)) >> 16;   // RNE bf16
}
__device__ __forceinline__ float bf_lo(unsigned int u) { return __uint_as_float(u << 16); }
__device__ __forceinline__ float bf_hi(unsigned int u) { return __uint_as_float(u & 0xffff0000u); }

// ---------------- degree / CSR build (XCD-partitioned) ----------------
// pid = blockIdx&7 (likely XCD on MI355X round-robin dispatch). Each pid
// group reads ALL edges (coalesced, L3-served) but only processes edges
// whose dst is in its 1/8 dst-range -> cnt/cursor/csr lines single-XCD.

__global__ __launch_bounds__(256) void k_count_part(const int* __restrict__ dst,
                                                    int* __restrict__ cnt, int E,
                                                    float pscale) {
    const int pid = blockIdx.x & 7;
    const int stride = (gridDim.x >> 3) * 256;
    for (int e = (blockIdx.x >> 3) * 256 + threadIdx.x; e < E; e += stride) {
        int d = dst[e];
        int p = (int)((float)d * pscale);
        p = p > 7 ? 7 : p;
        if (p == pid) atomicAdd(&cnt[d], 1);
    }
}

__global__ __launch_bounds__(256) void k_scan1(const int* __restrict__ cnt,
                                               int* __restrict__ rofs,
                                               int* __restrict__ bsum, int n) {
    __shared__ int s[256];
    int t = threadIdx.x;
    int i = blockIdx.x * 256 + t;
    int v = (i < n) ? cnt[i] : 0;
    s[t] = v;
    __syncthreads();
#pragma unroll
    for (int off = 1; off < 256; off <<= 1) {
        int x = (t >= off) ? s[t - off] : 0;
        __syncthreads();
        s[t] += x;
        __syncthreads();
    }
    if (i < n) rofs[i + 1] = s[t];
    if (t == 255) bsum[blockIdx.x] = s[255];
    if (i == 0) rofs[0] = 0;
}

__global__ __launch_bounds__(256) void k_scan2(int* __restrict__ bsum, int nb) {
    __shared__ int s[256];
    int t = threadIdx.x;
    int v = (t < nb) ? bsum[t] : 0;
    s[t] = v;
    __syncthreads();
#pragma unroll
    for (int off = 1; off < 256; off <<= 1) {
        int x = (t >= off) ? s[t - off] : 0;
        __syncthreads();
        s[t] += x;
        __syncthreads();
    }
    if (t < nb) bsum[t] = s[t] - v;
}

// finalize rofs, derive cursor and dinv in one pass
__global__ __launch_bounds__(256) void k_scan3(int* __restrict__ rofs,
                                               const int* __restrict__ bsum,
                                               const int* __restrict__ cnt,
                                               int* __restrict__ cursor,
                                               float* __restrict__ dinv, int n) {
    int i = blockIdx.x * 256 + threadIdx.x;
    if (i < n) {
        int incl = rofs[i + 1] + bsum[blockIdx.x];
        rofs[i + 1] = incl;
        int c = cnt[i];
        cursor[i] = incl - c;
        dinv[i] = rsqrtf((float)(c + 1));
    }
}

__global__ __launch_bounds__(256) void k_scatter_part(const int* __restrict__ src,
                                                      const int* __restrict__ dst,
                                                      int* __restrict__ cursor,
                                                      unsigned short* __restrict__ csr,
                                                      int E, float pscale) {
    const int pid = blockIdx.x & 7;
    const int stride = (gridDim.x >> 3) * 256;
    for (int e = (blockIdx.x >> 3) * 256 + threadIdx.x; e < E; e += stride) {
        int d = dst[e];
        int p = (int)((float)d * pscale);
        p = p > 7 ? 7 : p;
        if (p == pid) {
            int pos = atomicAdd(&cursor[d], 1);
            csr[pos] = (unsigned short)src[e];
        }
    }
}

// ---------------- W pre-pack: W[K][M] f32 -> Wp[(k/8)*Mp + n][8] bf16 ----------------
__global__ __launch_bounds__(256) void k_prepW(const float* __restrict__ W1,
                                               const float* __restrict__ W2,
                                               const float* __restrict__ W3,
                                               unsigned short* __restrict__ Wp1,
                                               unsigned short* __restrict__ Wp2,
                                               unsigned short* __restrict__ Wp3) {
    int t = blockIdx.x * 256 + threadIdx.x;
    const float* W; unsigned short* Wp; int M, Mp, kc, nn;
    if (t < 4096)        { W = W1; Wp = Wp1; M = 128; Mp = 128; kc = t >> 7; nn = t & 127; }
    else if (t < 6144)   { t -= 4096; W = W2; Wp = Wp2; M = 128; Mp = 128; kc = t >> 7; nn = t & 127; }
    else if (t < 6912)   { t -= 6144; W = W3; Wp = Wp3; M = 40;  Mp = 48;  kc = t / 48; nn = t % 48; }
    else return;
    FragU o;
#pragma unroll
    for (int j = 0; j < 8; ++j) {
        int k = kc * 8 + j;
        o.s[j] = (nn < M) ? (unsigned short)f2bf(W[k * M + nn]) : 0;
    }
    *(uint4*)&Wp[((size_t)kc * Mp + nn) * 8] = o.u;
}

// ---------------- MFMA GEMM, M=128 out, f32 A (layer 1) ----------------
template <int K>
__global__ __launch_bounds__(256) void gemm_mfma_f32A(const float* __restrict__ A,
                                                      const unsigned short* __restrict__ Wp,
                                                      const float* __restrict__ dinv,
                                                      unsigned short* __restrict__ hn, int n) {
    __shared__ unsigned short Wl[K * 128];
    const int t = threadIdx.x;
    const int w = t >> 6, lane = t & 63, sub = lane & 15, q = lane >> 4;
    const int row0 = blockIdx.x * 64 + w * 16;
    const int row = row0 + sub;
    const bool rv = row < n;
    const float* ap = A + (size_t)row * K;

    for (int sidx = t; sidx < (K * 128) / 8; sidx += 256)
        *(uint4*)&Wl[sidx * 8] = *(const uint4*)&Wp[(size_t)sidx * 8];
    __syncthreads();

    f32x4 acc[8];
#pragma unroll
    for (int cg = 0; cg < 8; ++cg) acc[cg] = (f32x4)0.f;

    for (int k0 = 0; k0 < K; k0 += 32) {
        FragU af; af.u = make_uint4(0, 0, 0, 0);
        if (rv) {
            float4 f0 = *(const float4*)(ap + k0 + q * 8);
            float4 f1 = *(const float4*)(ap + k0 + q * 8 + 4);
            af.h2[0] = __float22bfloat162_rn(make_float2(f0.x, f0.y));
            af.h2[1] = __float22bfloat162_rn(make_float2(f0.z, f0.w));
            af.h2[2] = __float22bfloat162_rn(make_float2(f1.x, f1.y));
            af.h2[3] = __float22bfloat162_rn(make_float2(f1.z, f1.w));
        }
        const int kc = (k0 >> 3) + q;
#pragma unroll
        for (int cg = 0; cg < 8; ++cg) {
            bf16x8 b = *(const bf16x8*)&Wl[(kc * 128 + cg * 16 + sub) * 8];
            acc[cg] = __builtin_amdgcn_mfma_f32_16x16x32_bf16(af.v, b, acc[cg], 0, 0, 0);
        }
    }

    const int rbase = row0 + q * 4;
    float dv[4];
#pragma unroll
    for (int r = 0; r < 4; ++r) dv[r] = (rbase + r < n) ? dinv[rbase + r] : 0.f;
#pragma unroll
    for (int cg = 0; cg < 8; ++cg)
#pragma unroll
        for (int r = 0; r < 4; ++r) {
            int rr = rbase + r;
            if (rr < n)
                hn[(size_t)rr * 128 + cg * 16 + sub] = (unsigned short)f2bf(acc[cg][r] * dv[r]);
        }
}

template <int K>
__global__ __launch_bounds__(256) void gemm_mfma_bf16A(const unsigned short* __restrict__ A,
                                                       const unsigned short* __restrict__ Wp,
                                                       const float* __restrict__ dinv,
                                                       unsigned short* __restrict__ hn, int n) {
    __shared__ unsigned short Wl[K * 128];
    const int t = threadIdx.x;
    const int w = t >> 6, lane = t & 63, sub = lane & 15, q = lane >> 4;
    const int row0 = blockIdx.x * 64 + w * 16;
    const int row = row0 + sub;
    const bool rv = row < n;
    const unsigned short* ap = A + (size_t)row * K;

    for (int sidx = t; sidx < (K * 128) / 8; sidx += 256)
        *(uint4*)&Wl[sidx * 8] = *(const uint4*)&Wp[(size_t)sidx * 8];
    __syncthreads();

    f32x4 acc[8];
#pragma unroll
    for (int cg = 0; cg < 8; ++cg) acc[cg] = (f32x4)0.f;

    for (int k0 = 0; k0 < K; k0 += 32) {
        FragU af; af.u = make_uint4(0, 0, 0, 0);
        if (rv) af.u = *(const uint4*)(ap + k0 + q * 8);
        const int kc = (k0 >> 3) + q;
#pragma unroll
        for (int cg = 0; cg < 8; ++cg) {
            bf16x8 b = *(const bf16x8*)&Wl[(kc * 128 + cg * 16 + sub) * 8];
            acc[cg] = __builtin_amdgcn_mfma_f32_16x16x32_bf16(af.v, b, acc[cg], 0, 0, 0);
        }
    }

    const int rbase = row0 + q * 4;
    float dv[4];
#pragma unroll
    for (int r = 0; r < 4; ++r) dv[r] = (rbase + r < n) ? dinv[rbase + r] : 0.f;
#pragma unroll
    for (int cg = 0; cg < 8; ++cg)
#pragma unroll
        for (int r = 0; r < 4; ++r) {
            int rr = rbase + r;
            if (rr < n)
                hn[(size_t)rr * 128 + cg * 16 + sub] = (unsigned short)f2bf(acc[cg][r] * dv[r]);
        }
}

// layer 3: K=128, M=40 (padded 48), bf16 A
__global__ __launch_bounds__(256) void gemm_mfma_m40(const unsigned short* __restrict__ A,
                                                     const unsigned short* __restrict__ Wp,
                                                     const float* __restrict__ dinv,
                                                     unsigned short* __restrict__ hn, int n) {
    const int K = 128;
    __shared__ unsigned short Wl[K * 48];
    const int t = threadIdx.x;
    const int w = t >> 6, lane = t & 63, sub = lane & 15, q = lane >> 4;
    const int row0 = blockIdx.x * 64 + w * 16;
    const int row = row0 + sub;
    const bool rv = row < n;
    const unsigned short* ap = A + (size_t)row * K;

    for (int sidx = t; sidx < (K * 48) / 8; sidx += 256)
        *(uint4*)&Wl[sidx * 8] = *(const uint4*)&Wp[(size_t)sidx * 8];
    __syncthreads();

    f32x4 acc[3];
#pragma unroll
    for (int cg = 0; cg < 3; ++cg) acc[cg] = (f32x4)0.f;

    for (int k0 = 0; k0 < K; k0 += 32) {
        FragU af; af.u = make_uint4(0, 0, 0, 0);
        if (rv) af.u = *(const uint4*)(ap + k0 + q * 8);
        const int kc = (k0 >> 3) + q;
#pragma unroll
        for (int cg = 0; cg < 3; ++cg) {
            bf16x8 b = *(const bf16x8*)&Wl[(kc * 48 + cg * 16 + sub) * 8];
            acc[cg] = __builtin_amdgcn_mfma_f32_16x16x32_bf16(af.v, b, acc[cg], 0, 0, 0);
        }
    }

    const int rbase = row0 + q * 4;
    float dv[4];
#pragma unroll
    for (int r = 0; r < 4; ++r) dv[r] = (rbase + r < n) ? dinv[rbase + r] : 0.f;
#pragma unroll
    for (int cg = 0; cg < 3; ++cg) {
        int col = cg * 16 + sub;
        if (col < 40) {
#pragma unroll
            for (int r = 0; r < 4; ++r) {
                int rr = rbase + r;
                if (rr < n)
                    hn[(size_t)rr * 40 + col] = (unsigned short)f2bf(acc[cg][r] * dv[r]);
            }
        }
    }
}

// ---------------- aggregation ----------------
__global__ __launch_bounds__(256) void agg128_bf16(const unsigned short* __restrict__ hn,
                                                   const int* __restrict__ rofs,
                                                   const unsigned short* __restrict__ csr,
                                                   const float* __restrict__ dinv,
                                                   const float* __restrict__ bias,
                                                   unsigned short* __restrict__ obf, int n) {
    int wid = (blockIdx.x * 256 + threadIdx.x) >> 6;
    if (wid >= n) return;
    const int v = wid;
    const int lane = threadIdx.x & 63;
    const int q = lane >> 4;
    const int sub = lane & 15;
    float acc[8];
#pragma unroll
    for (int k = 0; k < 8; ++k) acc[k] = 0.f;
    const int e0 = rofs[v];
    const int total = rofs[v + 1] - e0 + 1;   // + self loop at i==0
    int i = q;
    for (; i + 4 < total; i += 8) {
        int s0 = (i == 0) ? v : (int)csr[e0 + i - 1];
        int s1 = (int)csr[e0 + i + 3];
        uint4 u0 = *(const uint4*)(hn + (size_t)s0 * 128 + sub * 8);
        uint4 u1 = *(const uint4*)(hn + (size_t)s1 * 128 + sub * 8);
        acc[0] += bf_lo(u0.x); acc[1] += bf_hi(u0.x);
        acc[2] += bf_lo(u0.y); acc[3] += bf_hi(u0.y);
        acc[4] += bf_lo(u0.z); acc[5] += bf_hi(u0.z);
        acc[6] += bf_lo(u0.w); acc[7] += bf_hi(u0.w);
        acc[0] += bf_lo(u1.x); acc[1] += bf_hi(u1.x);
        acc[2] += bf_lo(u1.y); acc[3] += bf_hi(u1.y);
        acc[4] += bf_lo(u1.z); acc[5] += bf_hi(u1.z);
        acc[6] += bf_lo(u1.w); acc[7] += bf_hi(u1.w);
    }
    if (i < total) {
        int s = (i == 0) ? v : (int)csr[e0 + i - 1];
        uint4 u = *(const uint4*)(hn + (size_t)s * 128 + sub * 8);
        acc[0] += bf_lo(u.x); acc[1] += bf_hi(u.x);
        acc[2] += bf_lo(u.y); acc[3] += bf_hi(u.y);
        acc[4] += bf_lo(u.z); acc[5] += bf_hi(u.z);
        acc[6] += bf_lo(u.w); acc[7] += bf_hi(u.w);
    }
#pragma unroll
    for (int k = 0; k < 8; ++k) {
        acc[k] += __shfl_xor(acc[k], 16);
        acc[k] += __shfl_xor(acc[k], 32);
    }
    if (q == 0) {
        float dv = dinv[v];
        float4 b0 = *(const float4*)(bias + sub * 8);
        float4 b1 = *(const float4*)(bias + sub * 8 + 4);
        float o[8];
        o[0] = fmaxf(dv * acc[0] + b0.x, 0.f);
        o[1] = fmaxf(dv * acc[1] + b0.y, 0.f);
        o[2] = fmaxf(dv * acc[2] + b0.z, 0.f);
        o[3] = fmaxf(dv * acc[3] + b0.w, 0.f);
        o[4] = fmaxf(dv * acc[4] + b1.x, 0.f);
        o[5] = fmaxf(dv * acc[5] + b1.y, 0.f);
        o[6] = fmaxf(dv * acc[6] + b1.z, 0.f);
        o[7] = fmaxf(dv * acc[7] + b1.w, 0.f);
        uint4 pk;
        pk.x = f2bf(o[0]) | (f2bf(o[1]) << 16);
        pk.y = f2bf(o[2]) | (f2bf(o[3]) << 16);
        pk.z = f2bf(o[4]) | (f2bf(o[5]) << 16);
        pk.w = f2bf(o[6]) | (f2bf(o[7]) << 16);
        *(uint4*)(obf + (size_t)v * 128 + sub * 8) = pk;
    }
}

__global__ __launch_bounds__(256) void agg40_lsm_bf16(const unsigned short* __restrict__ hn,
                                                      const int* __restrict__ rofs,
                                                      const unsigned short* __restrict__ csr,
                                                      const float* __restrict__ dinv,
                                                      const float* __restrict__ bias,
                                                      float* __restrict__ out, int n) {
    int wid = (blockIdx.x * 256 + threadIdx.x) >> 6;
    if (wid >= n) return;
    const int v = wid;
    const int lane = threadIdx.x & 63;
    const int h = lane >> 5;
    const int sl = lane & 31;
    const bool act = sl < 20;
    float a0 = 0.f, a1 = 0.f;
    const int e0 = rofs[v];
    const int total = rofs[v + 1] - e0 + 1;
    int i = h;
    for (; i + 2 < total; i += 4) {
        int s0 = (i == 0) ? v : (int)csr[e0 + i - 1];
        int s1 = (int)csr[e0 + i + 1];
        if (act) {
            unsigned int u0 = *(const unsigned int*)(hn + (size_t)s0 * 40 + sl * 2);
            unsigned int u1 = *(const unsigned int*)(hn + (size_t)s1 * 40 + sl * 2);
            a0 += bf_lo(u0) + bf_lo(u1);
            a1 += bf_hi(u0) + bf_hi(u1);
        }
    }
    if (i < total) {
        int s = (i == 0) ? v : (int)csr[e0 + i - 1];
        if (act) {
            unsigned int u = *(const unsigned int*)(hn + (size_t)s * 40 + sl * 2);
            a0 += bf_lo(u);
            a1 += bf_hi(u);
        }
    }
    a0 += __shfl_xor(a0, 32);
    a1 += __shfl_xor(a1, 32);
    float dv = dinv[v];
    float v0 = act ? (dv * a0 + bias[sl * 2])     : -3.402823466e38f;
    float v1 = act ? (dv * a1 + bias[sl * 2 + 1]) : -3.402823466e38f;
    float m = fmaxf(v0, v1);
#pragma unroll
    for (int off = 16; off; off >>= 1) m = fmaxf(m, __shfl_xor(m, off));
    float p = act ? (__expf(v0 - m) + __expf(v1 - m)) : 0.f;
#pragma unroll
    for (int off = 16; off; off >>= 1) p += __shfl_xor(p, off);
    if (h == 0 && act) {
        float ls = __logf(p);
        *(float2*)(out + (size_t)v * 40 + sl * 2) = make_float2(v0 - m - ls, v1 - m - ls);
    }
}

// ---------------- launch ----------------

extern "C" void kernel_launch(void* const* d_in, const int* in_sizes, int n_in,
                              void* d_out, int out_size, void* d_ws, size_t ws_size,
                              hipStream_t stream) {
    const float* x     = (const float*)d_in[0];
    const int*   ei    = (const int*)d_in[1];
    const float* W_in  = (const float*)d_in[2];
    const float* b_in  = (const float*)d_in[3];
    const float* W_mid = (const float*)d_in[4];
    const float* b_mid = (const float*)d_in[5];
    const float* W_out = (const float*)d_in[6];
    const float* b_out = (const float*)d_in[7];
    float* out = (float*)d_out;

    const int N = in_sizes[0] / F_IN;   // 50000
    const int E = in_sizes[1] / 2;      // 800000
    const int* srcp = ei;
    const int* dstp = ei + E;
    const float pscale = 8.0f / (float)N;

    char* w = (char*)d_ws;
    unsigned short* hn  = (unsigned short*)w; w += (size_t)N * 128 * 2; // GEMM out (bf16)
    unsigned short* obf = (unsigned short*)w; w += (size_t)N * 128 * 2; // agg out (bf16)
    float* dinv = (float*)w; w += (size_t)N * 4;
    int* cnt    = (int*)w;   w += (size_t)N * 4;
    int* rofs   = (int*)w;   w += (size_t)(N + 1) * 4 + 12;  // keep 16B alignment
    int* cursor = (int*)w;   w += (size_t)N * 4;
    int* bsum   = (int*)w;   w += 1024;
    unsigned short* csr = (unsigned short*)w; w += (size_t)E * 2 + 2;
    unsigned short* Wp1 = (unsigned short*)((((size_t)w) + 15) & ~(size_t)15); w = (char*)Wp1 + 32 * 128 * 8 * 2;
    unsigned short* Wp2 = (unsigned short*)w; w += 16 * 128 * 8 * 2;
    unsigned short* Wp3 = (unsigned short*)w; w += 16 * 48 * 8 * 2;

    const int nbN = (N + 255) / 256;
    const int nbW = (N * 64 + 255) / 256;   // wave-per-node grids
    const int nbG = (N + 63) / 64;          // 64 rows per block
    const int nbP = 2048;                   // partitioned edge kernels (8 pid groups x 256)

    hipMemsetAsync(cnt, 0, (size_t)N * 4, stream);
    k_prepW<<<27, 256, 0, stream>>>(W_in, W_mid, W_out, Wp1, Wp2, Wp3);
    k_count_part<<<nbP, 256, 0, stream>>>(dstp, cnt, E, pscale);
    k_scan1<<<nbN, 256, 0, stream>>>(cnt, rofs, bsum, N);
    k_scan2<<<1, 256, 0, stream>>>(bsum, nbN);
    k_scan3<<<nbN, 256, 0, stream>>>(rofs, bsum, cnt, cursor, dinv, N);
    k_scatter_part<<<nbP, 256, 0, stream>>>(srcp, dstp, cursor, csr, E, pscale);

    // layer 1: x f32 -> hn bf16 -> obf bf16 (relu)
    gemm_mfma_f32A<256><<<nbG, 256, 0, stream>>>(x, Wp1, dinv, hn, N);
    agg128_bf16<<<nbW, 256, 0, stream>>>(hn, rofs, csr, dinv, b_in, obf, N);
    // layer 2
    gemm_mfma_bf16A<128><<<nbG, 256, 0, stream>>>(obf, Wp2, dinv, hn, N);
    agg128_bf16<<<nbW, 256, 0, stream>>>(hn, rofs, csr, dinv, b_mid, obf, N);
    // layer 3: obf -> hn[N,40] bf16 -> out f32 (log_softmax)
    gemm_mfma_m40<<<nbG, 256, 0, stream>>>(obf, Wp3, dinv, hn, N);
    agg40_lsm_bf16<<<nbW, 256, 0, stream>>>(hn, rofs, csr, dinv, b_out, out, N);
}